// Round 1
// baseline (9730.932 us; speedup 1.0000x reference)
//
#include <hip/hip_runtime.h>

// ---------------------------------------------------------------------------
// SubModel_22016002359901: 3x GCN(2 conv) + FC heads, N=100000, F=128, E=1.6M
// Round 1: correct f32 baseline.
//   - GEMM: tiled f32, BM=128/BK=32, 8x8 (or 8x4) per-thread register tile,
//     fused relu-in / relu-out / bias / Xs-accumulate epilogues.
//   - GCN aggregation: agg = b + dinv^2*h (init), then wave-per-edge atomic
//     scatter of h[src]*norm into agg[dst].
// ---------------------------------------------------------------------------

static __device__ __forceinline__ float frelu(float x) { return x > 0.f ? x : 0.f; }

// ---------------- small kernels ----------------
__global__ void fill_f32(float* __restrict__ p, float v, int n) {
    int i = blockIdx.x * blockDim.x + threadIdx.x;
    if (i < n) p[i] = v;
}

__global__ void deg_acc(const int* __restrict__ dst, const float* __restrict__ ew,
                        float* __restrict__ deg, int nE) {
    int e = blockIdx.x * blockDim.x + threadIdx.x;
    if (e < nE) atomicAdd(&deg[dst[e]], ew[e]);
}

__global__ void rsqrt_k(float* __restrict__ p, int n) {
    int i = blockIdx.x * blockDim.x + threadIdx.x;
    if (i < n) p[i] = rsqrtf(p[i]);
}

// agg[n][f] = bias[f] + dinv[n]^2 * h[n][f]   (self-loop term + bias fused init)
__global__ void agg_init(const float* __restrict__ h, const float* __restrict__ dinv,
                         const float* __restrict__ bias, float* __restrict__ agg, int n4) {
    int i = blockIdx.x * blockDim.x + threadIdx.x;  // float4 index over N*128/4
    if (i >= n4) return;
    int node = i >> 5;            // 32 float4 per row (F=128)
    int f4 = (i & 31) * 4;
    float di = dinv[node];
    float s = di * di;
    const float4 hv = *(const float4*)(h + (size_t)i * 4);
    const float4 b  = *(const float4*)(bias + f4);
    float4 o;
    o.x = b.x + s * hv.x; o.y = b.y + s * hv.y;
    o.z = b.z + s * hv.z; o.w = b.w + s * hv.w;
    *(float4*)(agg + (size_t)i * 4) = o;
}

// one wave (64 lanes) per edge; each lane handles 2 features (float2)
__global__ __launch_bounds__(256) void scatter_k(
    const int* __restrict__ src, const int* __restrict__ dst,
    const float* __restrict__ ew, const float* __restrict__ dinv,
    const float* __restrict__ h, float* __restrict__ agg, int nE) {
    size_t gt = (size_t)blockIdx.x * 256u + threadIdx.x;
    int e = (int)(gt >> 6);
    if (e >= nE) return;
    int lane = threadIdx.x & 63;
    int s = src[e], d = dst[e];
    float norm = dinv[s] * ew[e] * dinv[d];
    const float2 hv = *(const float2*)(h + (size_t)s * 128 + lane * 2);
    float* a = agg + (size_t)d * 128 + lane * 2;
    atomicAdd(a,     hv.x * norm);
    atomicAdd(a + 1, hv.y * norm);
}

// ---------------- tiled f32 GEMM ----------------
// C[nrows x M] = act( act_in(A[nrows x K]) @ W[K x M] + bias ), column tile BN.
// EPI: 0 = plain store; 2 = store to C and xs[row*64+col] += value.
template<int K, int BN, int RELU_IN, int RELU_OUT, int EPI>
__global__ __launch_bounds__(256, 2) void gemm_k(
    const float* __restrict__ A, const float* __restrict__ W,
    const float* __restrict__ bias, float* __restrict__ C,
    int M, int nrows, float* __restrict__ xs) {
    constexpr int BM = 128, BK = 32;
    constexpr int TN  = (BN >= 128) ? 8 : 4;
    constexpr int NTX = BN / TN;          // threads along cols
    constexpr int NTY = 256 / NTX;        // threads along rows
    constexpr int TM  = BM / NTY;         // rows per thread (=8)
    constexpr int WC  = (TN == 8) ? BN / 2 : BN;
    static_assert(NTX * NTY == 256, "thread layout");
    static_assert(TM == 8, "TM");

    __shared__ float As[BK][BM + 4];                       // transposed A tile
    __shared__ float Wa[BK][WC];                           // cols 8j..8j+3 (TN=8) or all (TN=4)
    __shared__ float Wb[(TN == 8) ? BK : 1][(TN == 8) ? WC : 4];  // cols 8j+4..8j+7

    const int tid  = threadIdx.x;
    const int tx   = tid % NTX;
    const int ty   = tid / NTX;
    const int row0 = blockIdx.x * BM;
    const int col0 = blockIdx.y * BN;

    float acc[TM][TN];
#pragma unroll
    for (int r = 0; r < TM; ++r)
#pragma unroll
        for (int c = 0; c < TN; ++c) acc[r][c] = 0.f;

    for (int k0 = 0; k0 < K; k0 += BK) {
        // ---- load A tile (BM x BK), store transposed ----
#pragma unroll
        for (int i = 0; i < (BM * BK) / (256 * 4); ++i) {
            int f  = tid + i * 256;       // float4 id
            int r  = f >> 3;              // 8 float4 per row of BK=32
            int kc = f & 7;
            float4 v = {0.f, 0.f, 0.f, 0.f};
            int grow = row0 + r;
            if (grow < nrows) v = *(const float4*)(A + (size_t)grow * K + k0 + kc * 4);
            if (RELU_IN) { v.x = frelu(v.x); v.y = frelu(v.y); v.z = frelu(v.z); v.w = frelu(v.w); }
            As[kc * 4 + 0][r] = v.x; As[kc * 4 + 1][r] = v.y;
            As[kc * 4 + 2][r] = v.z; As[kc * 4 + 3][r] = v.w;
        }
        // ---- load W tile (BK x BN) ----
#pragma unroll
        for (int i = 0; i < (BK * BN) / (256 * 4); ++i) {
            int f  = tid + i * 256;
            int r  = f / (BN / 4);
            int c4 = f % (BN / 4);
            float4 v = *(const float4*)(W + (size_t)(k0 + r) * M + col0 + c4 * 4);
            if (TN == 8) {
                int j = c4 >> 1;
                if (c4 & 1) *(float4*)&Wb[r][j * 4] = v;
                else        *(float4*)&Wa[r][j * 4] = v;
            } else {
                *(float4*)&Wa[r][c4 * 4] = v;
            }
        }
        __syncthreads();
        // ---- inner product ----
#pragma unroll
        for (int kk = 0; kk < BK; ++kk) {
            float4 a0 = *(const float4*)&As[kk][ty * TM + 0];
            float4 a1 = *(const float4*)&As[kk][ty * TM + 4];
            float av[8] = {a0.x, a0.y, a0.z, a0.w, a1.x, a1.y, a1.z, a1.w};
            if (TN == 8) {
                float4 w0 = *(const float4*)&Wa[kk][tx * 4];
                float4 w1 = *(const float4*)&Wb[kk][tx * 4];
                float wv[8] = {w0.x, w0.y, w0.z, w0.w, w1.x, w1.y, w1.z, w1.w};
#pragma unroll
                for (int r = 0; r < TM; ++r)
#pragma unroll
                    for (int c = 0; c < 8; ++c) acc[r][c] += av[r] * wv[c];
            } else {
                float4 w0 = *(const float4*)&Wa[kk][tx * 4];
                float wv[4] = {w0.x, w0.y, w0.z, w0.w};
#pragma unroll
                for (int r = 0; r < TM; ++r)
#pragma unroll
                    for (int c = 0; c < 4; ++c) acc[r][c] += av[r] * wv[c];
            }
        }
        __syncthreads();
    }

    // ---- epilogue ----
    float bv[TN];
#pragma unroll
    for (int c = 0; c < TN; ++c) bv[c] = bias ? bias[col0 + tx * TN + c] : 0.f;

#pragma unroll
    for (int r = 0; r < TM; ++r) {
        int grow = row0 + ty * TM + r;
        if (grow >= nrows) continue;
        float ov[TN];
#pragma unroll
        for (int c = 0; c < TN; ++c) {
            float v = acc[r][c] + bv[c];
            if (RELU_OUT) v = frelu(v);
            ov[c] = v;
        }
        float* cp = C + (size_t)grow * M + col0 + tx * TN;
        float4 s0 = {ov[0], ov[1], ov[2], ov[3]};
        *(float4*)cp = s0;
        if (TN == 8) {
            float4 s1 = {ov[4], ov[5], ov[6], ov[7]};
            *(float4*)(cp + 4) = s1;
        }
        if (EPI == 2) {  // xs += value (M==64, col0==0 path only)
            float* xp = xs + (size_t)grow * 64 + tx * TN;
            float4 o = *(const float4*)xp;
            o.x += ov[0]; o.y += ov[1]; o.z += ov[2]; o.w += ov[3];
            *(float4*)xp = o;
        }
    }
}

// ---------------------------------------------------------------------------
extern "C" void kernel_launch(void* const* d_in, const int* in_sizes, int n_in,
                              void* d_out, int out_size, void* d_ws, size_t ws_size,
                              hipStream_t stream) {
    (void)n_in; (void)out_size; (void)ws_size;
    const float* X = (const float*)d_in[0];
    const int N = in_sizes[0] / 128;

    const float* fc1_w1 = (const float*)d_in[19];
    const float* fc1_b1 = (const float*)d_in[20];
    const float* fc1_w2 = (const float*)d_in[21];
    const float* fc1_b2 = (const float*)d_in[22];
    const float* fc1_w3 = (const float*)d_in[23];
    const float* fc1_b3 = (const float*)d_in[24];
    const float* fc2_w1 = (const float*)d_in[25];
    const float* fc2_b1 = (const float*)d_in[26];
    const float* fc2_w2 = (const float*)d_in[27];
    const float* fc2_b2 = (const float*)d_in[28];
    const float* fc2_w3 = (const float*)d_in[29];
    const float* fc2_b3 = (const float*)d_in[30];

    float* out = (float*)d_out;
    float* Xs  = out;  // slot 0

    // workspace layout (floats)
    const size_t NF = (size_t)N * 128;
    float* ws   = (float*)d_ws;
    float* dinv = ws;                                  // N (padded)
    float* h    = ws + (((size_t)N + 255) / 256) * 256; // N*128  (also reused as t2)
    float* agg  = h + NF;                               // N*128
    float* t1   = agg + NF;                             // N*256

    const dim3 blk(256);
    const int GR = (N + 127) / 128;   // GEMM row blocks

    // ---------------- X0 = fc1(X)  -> Xs ----------------
    gemm_k<128, 128, 0, 1, 0><<<dim3(GR, 2), blk, 0, stream>>>(X, fc1_w1, fc1_b1, t1, 256, N, nullptr);
    gemm_k<256, 128, 0, 1, 0><<<dim3(GR, 1), blk, 0, stream>>>(t1, fc1_w2, fc1_b2, h, 128, N, nullptr);
    gemm_k<128, 64, 0, 1, 0><<<dim3(GR, 1), blk, 0, stream>>>(h, fc1_w3, fc1_b3, Xs, 64, N, nullptr);

    // ---------------- graphs ----------------
    for (int g = 0; g < 3; ++g) {
        const int*   ei  = (const int*)d_in[1 + 6 * g];
        const int    E   = in_sizes[1 + 6 * g] / 2;
        const int*   srp = ei;
        const int*   dsp = ei + E;
        const float* ew  = (const float*)d_in[2 + 6 * g];
        const float* w1  = (const float*)d_in[3 + 6 * g];
        const float* b1  = (const float*)d_in[4 + 6 * g];
        const float* w2  = (const float*)d_in[5 + 6 * g];
        const float* b2  = (const float*)d_in[6 + 6 * g];

        // deg -> dinv
        fill_f32<<<(N + 255) / 256, blk, 0, stream>>>(dinv, 1.f, N);
        deg_acc<<<(E + 255) / 256, blk, 0, stream>>>(dsp, ew, dinv, E);
        rsqrt_k<<<(N + 255) / 256, blk, 0, stream>>>(dinv, N);

        // conv1: h = X @ w1 ; agg = b1 + dinv^2 h + scatter
        gemm_k<128, 128, 0, 0, 0><<<dim3(GR, 1), blk, 0, stream>>>(X, w1, nullptr, h, 128, N, nullptr);
        agg_init<<<(N * 32 + 255) / 256, blk, 0, stream>>>(h, dinv, b1, agg, N * 32);
        scatter_k<<<(E + 3) / 4, blk, 0, stream>>>(srp, dsp, ew, dinv, h, agg, E);

        // conv2: h = relu(agg) @ w2 ; agg = b2 + dinv^2 h + scatter
        gemm_k<128, 128, 1, 0, 0><<<dim3(GR, 1), blk, 0, stream>>>(agg, w2, nullptr, h, 128, N, nullptr);
        agg_init<<<(N * 32 + 255) / 256, blk, 0, stream>>>(h, dinv, b2, agg, N * 32);
        scatter_k<<<(E + 3) / 4, blk, 0, stream>>>(srp, dsp, ew, dinv, h, agg, E);

        // fc2 head on relu(agg): t1 -> t2(h) -> z (out slot, += Xs)
        gemm_k<128, 128, 1, 1, 0><<<dim3(GR, 2), blk, 0, stream>>>(agg, fc2_w1, fc2_b1, t1, 256, N, nullptr);
        gemm_k<256, 128, 0, 1, 0><<<dim3(GR, 1), blk, 0, stream>>>(t1, fc2_w2, fc2_b2, h, 128, N, nullptr);
        gemm_k<128, 64, 0, 1, 2><<<dim3(GR, 1), blk, 0, stream>>>(
            h, fc2_w3, fc2_b3, out + (size_t)(1 + g) * N * 64, 64, N, Xs);
    }
}

// Round 2
// 3074.516 us; speedup vs baseline: 3.1650x; 3.1650x over previous
//
#include <hip/hip_runtime.h>

// ---------------------------------------------------------------------------
// SubModel_22016002359901: 3x GCN(2 conv) + FC heads, N=100000, F=128, E=1.6M
// Round 2: replace atomic scatter (80% of runtime) with CSR counting-sort +
// wave-per-node gather (atomic-free feature aggregation, self-loop fused).
// GEMMs unchanged from round 1.
// ---------------------------------------------------------------------------

static __device__ __forceinline__ float frelu(float x) { return x > 0.f ? x : 0.f; }

// ---------------- small kernels ----------------
// deg[i]=1.0 (self-loop weight), cnt[i]=0
__global__ void init_deg_cnt(float* __restrict__ deg, int* __restrict__ cnt, int n) {
    int i = blockIdx.x * blockDim.x + threadIdx.x;
    if (i < n) { deg[i] = 1.f; cnt[i] = 0; }
}

__global__ void deg_cnt(const int* __restrict__ dst, const float* __restrict__ ew,
                        float* __restrict__ deg, int* __restrict__ cnt, int nE) {
    int e = blockIdx.x * blockDim.x + threadIdx.x;
    if (e < nE) {
        int d = dst[e];
        atomicAdd(&deg[d], ew[e]);
        atomicAdd(&cnt[d], 1);
    }
}

__global__ void rsqrt_k(float* __restrict__ p, int n) {
    int i = blockIdx.x * blockDim.x + threadIdx.x;
    if (i < n) p[i] = rsqrtf(p[i]);
}

// ---- exclusive scan over cnt[n] -> rp[n+1], plus cursor copy ----
__global__ void scan1(const int* __restrict__ cnt, int* __restrict__ rp,
                      int* __restrict__ bsum, int n) {
    __shared__ int s[256];
    int i = blockIdx.x * 256 + threadIdx.x;
    int v = (i < n) ? cnt[i] : 0;
    s[threadIdx.x] = v;
    __syncthreads();
#pragma unroll
    for (int off = 1; off < 256; off <<= 1) {
        int x = (threadIdx.x >= off) ? s[threadIdx.x - off] : 0;
        __syncthreads();
        s[threadIdx.x] += x;
        __syncthreads();
    }
    if (i < n) rp[i] = s[threadIdx.x] - v;           // exclusive
    if (threadIdx.x == 255) bsum[blockIdx.x] = s[255];
}

__global__ void scan2(int* __restrict__ bsum, int nb) {  // single block of 512
    __shared__ int s[512];
    int t = threadIdx.x;
    int v = (t < nb) ? bsum[t] : 0;
    s[t] = v;
    __syncthreads();
#pragma unroll
    for (int off = 1; off < 512; off <<= 1) {
        int x = (t >= off) ? s[t - off] : 0;
        __syncthreads();
        s[t] += x;
        __syncthreads();
    }
    if (t < nb) bsum[t] = s[t] - v;                   // exclusive
}

__global__ void scan3(int* __restrict__ rp, const int* __restrict__ bsum,
                      int* __restrict__ cursor, int n, int E) {
    int i = blockIdx.x * 256 + threadIdx.x;
    if (i < n) {
        int v = rp[i] + bsum[i >> 8];
        rp[i] = v;
        cursor[i] = v;
    }
    if (i == 0) rp[n] = E;
}

// placement: sort edges by dst via cursor
__global__ void place_k(const int* __restrict__ src, const int* __restrict__ dst,
                        const float* __restrict__ ew, const float* __restrict__ dinv,
                        int* __restrict__ cursor, int* __restrict__ colv,
                        float* __restrict__ normv, int nE) {
    int e = blockIdx.x * blockDim.x + threadIdx.x;
    if (e >= nE) return;
    int s = src[e], d = dst[e];
    int p = atomicAdd(&cursor[d], 1);
    colv[p] = s;
    normv[p] = dinv[s] * ew[e] * dinv[d];
}

// one wave per node: agg[n] = bias + dinv[n]^2*h[n] + sum_e norm[e]*h[col[e]]
__global__ __launch_bounds__(256) void gather_k(
    const int* __restrict__ rp, const int* __restrict__ colv,
    const float* __restrict__ normv, const float* __restrict__ h,
    const float* __restrict__ dinv, const float* __restrict__ bias,
    float* __restrict__ agg, int n) {
    int node = (int)(((size_t)blockIdx.x * 256 + threadIdx.x) >> 6);
    if (node >= n) return;
    int lane = threadIdx.x & 63;
    float di = dinv[node];
    float sl = di * di;
    const float2 hv = *(const float2*)(h + (size_t)node * 128 + lane * 2);
    const float2 bv = *(const float2*)(bias + lane * 2);
    float2 acc0 = {bv.x + sl * hv.x, bv.y + sl * hv.y};
    float2 acc1 = {0.f, 0.f};
    int beg = rp[node], end = rp[node + 1];
    int i = beg;
    for (; i + 1 < end; i += 2) {
        int s0 = colv[i], s1 = colv[i + 1];
        float n0 = normv[i], n1 = normv[i + 1];
        const float2 v0 = *(const float2*)(h + (size_t)s0 * 128 + lane * 2);
        const float2 v1 = *(const float2*)(h + (size_t)s1 * 128 + lane * 2);
        acc0.x += n0 * v0.x; acc0.y += n0 * v0.y;
        acc1.x += n1 * v1.x; acc1.y += n1 * v1.y;
    }
    if (i < end) {
        int s0 = colv[i];
        float n0 = normv[i];
        const float2 v0 = *(const float2*)(h + (size_t)s0 * 128 + lane * 2);
        acc0.x += n0 * v0.x; acc0.y += n0 * v0.y;
    }
    float2 o = {acc0.x + acc1.x, acc0.y + acc1.y};
    *(float2*)(agg + (size_t)node * 128 + lane * 2) = o;
}

// ---------------- tiled f32 GEMM (unchanged) ----------------
template<int K, int BN, int RELU_IN, int RELU_OUT, int EPI>
__global__ __launch_bounds__(256, 2) void gemm_k(
    const float* __restrict__ A, const float* __restrict__ W,
    const float* __restrict__ bias, float* __restrict__ C,
    int M, int nrows, float* __restrict__ xs) {
    constexpr int BM = 128, BK = 32;
    constexpr int TN  = (BN >= 128) ? 8 : 4;
    constexpr int NTX = BN / TN;
    constexpr int NTY = 256 / NTX;
    constexpr int TM  = BM / NTY;
    constexpr int WC  = (TN == 8) ? BN / 2 : BN;
    static_assert(NTX * NTY == 256, "thread layout");
    static_assert(TM == 8, "TM");

    __shared__ float As[BK][BM + 4];
    __shared__ float Wa[BK][WC];
    __shared__ float Wb[(TN == 8) ? BK : 1][(TN == 8) ? WC : 4];

    const int tid  = threadIdx.x;
    const int tx   = tid % NTX;
    const int ty   = tid / NTX;
    const int row0 = blockIdx.x * BM;
    const int col0 = blockIdx.y * BN;

    float acc[TM][TN];
#pragma unroll
    for (int r = 0; r < TM; ++r)
#pragma unroll
        for (int c = 0; c < TN; ++c) acc[r][c] = 0.f;

    for (int k0 = 0; k0 < K; k0 += BK) {
#pragma unroll
        for (int i = 0; i < (BM * BK) / (256 * 4); ++i) {
            int f  = tid + i * 256;
            int r  = f >> 3;
            int kc = f & 7;
            float4 v = {0.f, 0.f, 0.f, 0.f};
            int grow = row0 + r;
            if (grow < nrows) v = *(const float4*)(A + (size_t)grow * K + k0 + kc * 4);
            if (RELU_IN) { v.x = frelu(v.x); v.y = frelu(v.y); v.z = frelu(v.z); v.w = frelu(v.w); }
            As[kc * 4 + 0][r] = v.x; As[kc * 4 + 1][r] = v.y;
            As[kc * 4 + 2][r] = v.z; As[kc * 4 + 3][r] = v.w;
        }
#pragma unroll
        for (int i = 0; i < (BK * BN) / (256 * 4); ++i) {
            int f  = tid + i * 256;
            int r  = f / (BN / 4);
            int c4 = f % (BN / 4);
            float4 v = *(const float4*)(W + (size_t)(k0 + r) * M + col0 + c4 * 4);
            if (TN == 8) {
                int j = c4 >> 1;
                if (c4 & 1) *(float4*)&Wb[r][j * 4] = v;
                else        *(float4*)&Wa[r][j * 4] = v;
            } else {
                *(float4*)&Wa[r][c4 * 4] = v;
            }
        }
        __syncthreads();
#pragma unroll
        for (int kk = 0; kk < BK; ++kk) {
            float4 a0 = *(const float4*)&As[kk][ty * TM + 0];
            float4 a1 = *(const float4*)&As[kk][ty * TM + 4];
            float av[8] = {a0.x, a0.y, a0.z, a0.w, a1.x, a1.y, a1.z, a1.w};
            if (TN == 8) {
                float4 w0 = *(const float4*)&Wa[kk][tx * 4];
                float4 w1 = *(const float4*)&Wb[kk][tx * 4];
                float wv[8] = {w0.x, w0.y, w0.z, w0.w, w1.x, w1.y, w1.z, w1.w};
#pragma unroll
                for (int r = 0; r < TM; ++r)
#pragma unroll
                    for (int c = 0; c < 8; ++c) acc[r][c] += av[r] * wv[c];
            } else {
                float4 w0 = *(const float4*)&Wa[kk][tx * 4];
                float wv[4] = {w0.x, w0.y, w0.z, w0.w};
#pragma unroll
                for (int r = 0; r < TM; ++r)
#pragma unroll
                    for (int c = 0; c < 4; ++c) acc[r][c] += av[r] * wv[c];
            }
        }
        __syncthreads();
    }

    float bv[TN];
#pragma unroll
    for (int c = 0; c < TN; ++c) bv[c] = bias ? bias[col0 + tx * TN + c] : 0.f;

#pragma unroll
    for (int r = 0; r < TM; ++r) {
        int grow = row0 + ty * TM + r;
        if (grow >= nrows) continue;
        float ov[TN];
#pragma unroll
        for (int c = 0; c < TN; ++c) {
            float v = acc[r][c] + bv[c];
            if (RELU_OUT) v = frelu(v);
            ov[c] = v;
        }
        float* cp = C + (size_t)grow * M + col0 + tx * TN;
        float4 s0 = {ov[0], ov[1], ov[2], ov[3]};
        *(float4*)cp = s0;
        if (TN == 8) {
            float4 s1 = {ov[4], ov[5], ov[6], ov[7]};
            *(float4*)(cp + 4) = s1;
        }
        if (EPI == 2) {
            float* xp = xs + (size_t)grow * 64 + tx * TN;
            float4 o = *(const float4*)xp;
            o.x += ov[0]; o.y += ov[1]; o.z += ov[2]; o.w += ov[3];
            *(float4*)xp = o;
        }
    }
}

// ---------------------------------------------------------------------------
extern "C" void kernel_launch(void* const* d_in, const int* in_sizes, int n_in,
                              void* d_out, int out_size, void* d_ws, size_t ws_size,
                              hipStream_t stream) {
    (void)n_in; (void)out_size; (void)ws_size;
    const float* X = (const float*)d_in[0];
    const int N = in_sizes[0] / 128;

    const float* fc1_w1 = (const float*)d_in[19];
    const float* fc1_b1 = (const float*)d_in[20];
    const float* fc1_w2 = (const float*)d_in[21];
    const float* fc1_b2 = (const float*)d_in[22];
    const float* fc1_w3 = (const float*)d_in[23];
    const float* fc1_b3 = (const float*)d_in[24];
    const float* fc2_w1 = (const float*)d_in[25];
    const float* fc2_b1 = (const float*)d_in[26];
    const float* fc2_w2 = (const float*)d_in[27];
    const float* fc2_b2 = (const float*)d_in[28];
    const float* fc2_w3 = (const float*)d_in[29];
    const float* fc2_b3 = (const float*)d_in[30];

    float* out = (float*)d_out;
    float* Xs  = out;  // slot 0

    // workspace layout (floats)
    const size_t NF = (size_t)N * 128;
    float* ws   = (float*)d_ws;
    float* dinv = ws;                                   // N (padded to 256)
    float* h    = ws + (((size_t)N + 255) / 256) * 256; // N*128 (also t2)
    float* agg  = h + NF;                               // N*128
    float* t1   = agg + NF;                             // N*256

    const dim3 blk(256);
    const int GR  = (N + 127) / 128;     // GEMM row blocks
    const int NB  = (N + 255) / 256;     // 1D node blocks (=391 for N=100000)
    const int GWB = (int)(((size_t)N * 64 + 255) / 256);  // wave-per-node blocks

    // ---------------- X0 = fc1(X)  -> Xs ----------------
    gemm_k<128, 128, 0, 1, 0><<<dim3(GR, 2), blk, 0, stream>>>(X, fc1_w1, fc1_b1, t1, 256, N, nullptr);
    gemm_k<256, 128, 0, 1, 0><<<dim3(GR, 1), blk, 0, stream>>>(t1, fc1_w2, fc1_b2, h, 128, N, nullptr);
    gemm_k<128, 64, 0, 1, 0><<<dim3(GR, 1), blk, 0, stream>>>(h, fc1_w3, fc1_b3, Xs, 64, N, nullptr);

    // ---------------- graphs ----------------
    for (int g = 0; g < 3; ++g) {
        const int*   ei  = (const int*)d_in[1 + 6 * g];
        const int    E   = in_sizes[1 + 6 * g] / 2;
        const int*   srp = ei;
        const int*   dsp = ei + E;
        const float* ew  = (const float*)d_in[2 + 6 * g];
        const float* w1  = (const float*)d_in[3 + 6 * g];
        const float* b1  = (const float*)d_in[4 + 6 * g];
        const float* w2  = (const float*)d_in[5 + 6 * g];
        const float* b2  = (const float*)d_in[6 + 6 * g];

        // CSR arrays alias t1 (t1 not live during conv phase)
        int*   cnt   = (int*)t1;           // N   (doubles as cursor)
        int*   rpn   = cnt + N;            // N+1
        int*   colv  = rpn + (N + 1);      // E
        float* normv = (float*)(colv + E); // E
        int*   bsum  = (int*)(normv + E);  // 512

        // ---- build CSR + dinv ----
        init_deg_cnt<<<NB, blk, 0, stream>>>(dinv, cnt, N);
        deg_cnt<<<(E + 255) / 256, blk, 0, stream>>>(dsp, ew, dinv, cnt, E);
        rsqrt_k<<<NB, blk, 0, stream>>>(dinv, N);
        scan1<<<NB, blk, 0, stream>>>(cnt, rpn, bsum, N);
        scan2<<<1, 512, 0, stream>>>(bsum, NB);
        scan3<<<NB, blk, 0, stream>>>(rpn, bsum, cnt, N, E);   // cnt becomes cursor
        place_k<<<(E + 255) / 256, blk, 0, stream>>>(srp, dsp, ew, dinv, cnt, colv, normv, E);

        // conv1: h = X @ w1 ; agg = b1 + dinv^2 h + gather
        gemm_k<128, 128, 0, 0, 0><<<dim3(GR, 1), blk, 0, stream>>>(X, w1, nullptr, h, 128, N, nullptr);
        gather_k<<<GWB, blk, 0, stream>>>(rpn, colv, normv, h, dinv, b1, agg, N);

        // conv2: h = relu(agg) @ w2 ; agg = b2 + dinv^2 h + gather
        gemm_k<128, 128, 1, 0, 0><<<dim3(GR, 1), blk, 0, stream>>>(agg, w2, nullptr, h, 128, N, nullptr);
        gather_k<<<GWB, blk, 0, stream>>>(rpn, colv, normv, h, dinv, b2, agg, N);

        // fc2 head on relu(agg): t1 -> t2(h) -> z (out slot, += Xs)
        gemm_k<128, 128, 1, 1, 0><<<dim3(GR, 2), blk, 0, stream>>>(agg, fc2_w1, fc2_b1, t1, 256, N, nullptr);
        gemm_k<256, 128, 0, 1, 0><<<dim3(GR, 1), blk, 0, stream>>>(t1, fc2_w2, fc2_b2, h, 128, N, nullptr);
        gemm_k<128, 64, 0, 1, 2><<<dim3(GR, 1), blk, 0, stream>>>(
            h, fc2_w3, fc2_b3, out + (size_t)(1 + g) * N * 64, 64, N, Xs);
    }
}

// Round 3
// 1886.367 us; speedup vs baseline: 5.1586x; 1.6299x over previous
//
#include <hip/hip_runtime.h>

// ---------------------------------------------------------------------------
// SubModel_22016002359901: 3x GCN(2 conv) + FC heads, N=100000, F=128, E=1.6M
// Round 3: bf16 MFMA GEMMs (16x16x32), bf16 activations end-to-end,
// bf16 gather. CSR build unchanged.
// ---------------------------------------------------------------------------

typedef short bf16x8 __attribute__((ext_vector_type(8)));
typedef float f32x4 __attribute__((ext_vector_type(4)));

static __device__ __forceinline__ float frelu(float x) { return x > 0.f ? x : 0.f; }

static __device__ __forceinline__ unsigned short f2bf(float f) {
    unsigned int u = __float_as_uint(f);
    u += 0x7fffu + ((u >> 16) & 1u);           // RNE
    return (unsigned short)(u >> 16);
}
static __device__ __forceinline__ float bflo(unsigned int u) {
    return __uint_as_float(u << 16);
}
static __device__ __forceinline__ float bfhi(unsigned int u) {
    return __uint_as_float(u & 0xffff0000u);
}

// ---------------- conversion kernels ----------------
__global__ void xconv(const float* __restrict__ src, unsigned short* __restrict__ dst, int n4) {
    int i = blockIdx.x * 256 + threadIdx.x;
    if (i >= n4) return;
    float4 v = *(const float4*)(src + (size_t)i * 4);
    ushort4 o = {f2bf(v.x), f2bf(v.y), f2bf(v.z), f2bf(v.w)};
    *(ushort4*)(dst + (size_t)i * 4) = o;
}

// dst[m][k] = bf16(src[k][m])   (transpose + convert, tiny)
__global__ void wtrans(const float* __restrict__ src, unsigned short* __restrict__ dst,
                       int K, int M) {
    int i = blockIdx.x * 256 + threadIdx.x;
    if (i >= K * M) return;
    int m = i / K, k = i % K;
    dst[i] = f2bf(src[(size_t)k * M + m]);
}

// ---------------- CSR build ----------------
__global__ void init_deg_cnt(float* __restrict__ deg, int* __restrict__ cnt, int n) {
    int i = blockIdx.x * blockDim.x + threadIdx.x;
    if (i < n) { deg[i] = 1.f; cnt[i] = 0; }
}

__global__ void deg_cnt(const int* __restrict__ dst, const float* __restrict__ ew,
                        float* __restrict__ deg, int* __restrict__ cnt, int nE) {
    int e = blockIdx.x * blockDim.x + threadIdx.x;
    if (e < nE) {
        int d = dst[e];
        atomicAdd(&deg[d], ew[e]);
        atomicAdd(&cnt[d], 1);
    }
}

__global__ void rsqrt_k(float* __restrict__ p, int n) {
    int i = blockIdx.x * blockDim.x + threadIdx.x;
    if (i < n) p[i] = rsqrtf(p[i]);
}

__global__ void scan1(const int* __restrict__ cnt, int* __restrict__ rp,
                      int* __restrict__ bsum, int n) {
    __shared__ int s[256];
    int i = blockIdx.x * 256 + threadIdx.x;
    int v = (i < n) ? cnt[i] : 0;
    s[threadIdx.x] = v;
    __syncthreads();
#pragma unroll
    for (int off = 1; off < 256; off <<= 1) {
        int x = (threadIdx.x >= off) ? s[threadIdx.x - off] : 0;
        __syncthreads();
        s[threadIdx.x] += x;
        __syncthreads();
    }
    if (i < n) rp[i] = s[threadIdx.x] - v;
    if (threadIdx.x == 255) bsum[blockIdx.x] = s[255];
}

__global__ void scan2(int* __restrict__ bsum, int nb) {
    __shared__ int s[512];
    int t = threadIdx.x;
    int v = (t < nb) ? bsum[t] : 0;
    s[t] = v;
    __syncthreads();
#pragma unroll
    for (int off = 1; off < 512; off <<= 1) {
        int x = (t >= off) ? s[t - off] : 0;
        __syncthreads();
        s[t] += x;
        __syncthreads();
    }
    if (t < nb) bsum[t] = s[t] - v;
}

__global__ void scan3(int* __restrict__ rp, const int* __restrict__ bsum,
                      int* __restrict__ cursor, int n, int E) {
    int i = blockIdx.x * 256 + threadIdx.x;
    if (i < n) {
        int v = rp[i] + bsum[i >> 8];
        rp[i] = v;
        cursor[i] = v;
    }
    if (i == 0) rp[n] = E;
}

__global__ void place_k(const int* __restrict__ src, const int* __restrict__ dst,
                        const float* __restrict__ ew, const float* __restrict__ dinv,
                        int* __restrict__ cursor, int* __restrict__ colv,
                        float* __restrict__ normv, int nE) {
    int e = blockIdx.x * blockDim.x + threadIdx.x;
    if (e >= nE) return;
    int s = src[e], d = dst[e];
    int p = atomicAdd(&cursor[d], 1);
    colv[p] = s;
    normv[p] = dinv[s] * ew[e] * dinv[d];
}

// one wave per node: aggr[n] = relu(bias + dinv^2*h[n] + sum norm*h[col]) (bf16 in/out)
__global__ __launch_bounds__(256) void gather_bf(
    const int* __restrict__ rp, const int* __restrict__ colv,
    const float* __restrict__ normv, const unsigned short* __restrict__ h,
    const float* __restrict__ dinv, const float* __restrict__ bias,
    unsigned short* __restrict__ aggr, int n) {
    int node = (int)(((size_t)blockIdx.x * 256 + threadIdx.x) >> 6);
    if (node >= n) return;
    int lane = threadIdx.x & 63;
    float di = dinv[node];
    float sl = di * di;
    unsigned int hu = *(const unsigned int*)(h + (size_t)node * 128 + lane * 2);
    float2 bv = *(const float2*)(bias + lane * 2);
    float ax = bv.x + sl * bflo(hu);
    float ay = bv.y + sl * bfhi(hu);
    float bx = 0.f, by = 0.f;
    int beg = rp[node], end = rp[node + 1];
    int i = beg;
    for (; i + 1 < end; i += 2) {
        int s0 = colv[i], s1 = colv[i + 1];
        float n0 = normv[i], n1 = normv[i + 1];
        unsigned int u0 = *(const unsigned int*)(h + (size_t)s0 * 128 + lane * 2);
        unsigned int u1 = *(const unsigned int*)(h + (size_t)s1 * 128 + lane * 2);
        ax += n0 * bflo(u0); ay += n0 * bfhi(u0);
        bx += n1 * bflo(u1); by += n1 * bfhi(u1);
    }
    if (i < end) {
        int s0 = colv[i];
        float n0 = normv[i];
        unsigned int u0 = *(const unsigned int*)(h + (size_t)s0 * 128 + lane * 2);
        ax += n0 * bflo(u0); ay += n0 * bfhi(u0);
    }
    float ox = frelu(ax + bx), oy = frelu(ay + by);
    unsigned int o = (unsigned int)f2bf(ox) | ((unsigned int)f2bf(oy) << 16);
    *(unsigned int*)(aggr + (size_t)node * 128 + lane * 2) = o;
}

// ---------------- bf16 MFMA GEMM ----------------
// C[nrows x M] = act(A[nrows x K](bf16) @ Wt^T + bias)
// Wt is [M][K] bf16 (transposed weights). BM=128, BN=64, BK=64, 4 waves (2x2).
// EPI: 0 = bf16 store; 1 = f32 store; 2 = f32 store + xs[row*64+col] += v.
template<int K, int RELU, int EPI>
__global__ __launch_bounds__(256, 2) void gemm_bf(
    const unsigned short* __restrict__ A, const unsigned short* __restrict__ Wt,
    const float* __restrict__ bias, void* __restrict__ Cout,
    int M, int nrows, float* __restrict__ xs) {
    constexpr int BM = 128, BN = 64, BK = 64;
    __shared__ unsigned short As[BM][BK + 8];   // stride 72 shorts = 144B (16B-aligned rows)
    __shared__ unsigned short Bs[BN][BK + 8];

    const int tid  = threadIdx.x;
    const int wid  = tid >> 6;
    const int lane = tid & 63;
    const int wm   = (wid >> 1) * 64;     // wave row offset in tile
    const int wn   = (wid & 1) * 32;      // wave col offset in tile
    const int row0 = blockIdx.x * BM;
    const int col0 = blockIdx.y * BN;
    const int lr   = lane & 15;           // fragment row/col selector
    const int lk   = (lane >> 4) * 8;     // fragment k offset

    f32x4 acc[4][2] = {};

    for (int k0 = 0; k0 < K; k0 += BK) {
        // stage A: 128 rows x 8 granules of 8 bf16
#pragma unroll
        for (int it = 0; it < 4; ++it) {
            int f = tid + it * 256;
            int r = f >> 3, g = f & 7;
            int grow = row0 + r;
            if (grow >= nrows) grow = nrows - 1;   // clamp (rows >= nrows never stored)
            bf16x8 v = *(const bf16x8*)(A + (size_t)grow * K + k0 + g * 8);
            *(bf16x8*)&As[r][g * 8] = v;
        }
        // stage B: 64 rows (cols of C) x 8 granules
#pragma unroll
        for (int it = 0; it < 2; ++it) {
            int f = tid + it * 256;
            int nidx = f >> 3, g = f & 7;
            bf16x8 v = *(const bf16x8*)(Wt + (size_t)(col0 + nidx) * K + k0 + g * 8);
            *(bf16x8*)&Bs[nidx][g * 8] = v;
        }
        __syncthreads();
#pragma unroll
        for (int kk = 0; kk < 2; ++kk) {
            bf16x8 af[4], bfv[2];
#pragma unroll
            for (int mi = 0; mi < 4; ++mi)
                af[mi] = *(const bf16x8*)&As[wm + 16 * mi + lr][kk * 32 + lk];
#pragma unroll
            for (int ni = 0; ni < 2; ++ni)
                bfv[ni] = *(const bf16x8*)&Bs[wn + 16 * ni + lr][kk * 32 + lk];
#pragma unroll
            for (int mi = 0; mi < 4; ++mi)
#pragma unroll
                for (int ni = 0; ni < 2; ++ni)
                    acc[mi][ni] = __builtin_amdgcn_mfma_f32_16x16x32_bf16(
                        af[mi], bfv[ni], acc[mi][ni], 0, 0, 0);
        }
        __syncthreads();
    }

    // epilogue: D[row=(lane>>4)*4+reg][col=lane&15] per 16x16 fragment
    const int dr0 = (lane >> 4) * 4;
#pragma unroll
    for (int ni = 0; ni < 2; ++ni) {
        int col = col0 + wn + 16 * ni + lr;
        float bv = bias ? bias[col] : 0.f;
#pragma unroll
        for (int mi = 0; mi < 4; ++mi) {
#pragma unroll
            for (int r = 0; r < 4; ++r) {
                int grow = row0 + wm + 16 * mi + dr0 + r;
                if (grow >= nrows) continue;
                float v = acc[mi][ni][r] + bv;
                if (RELU) v = frelu(v);
                if (EPI == 0) {
                    ((unsigned short*)Cout)[(size_t)grow * M + col] = f2bf(v);
                } else {
                    ((float*)Cout)[(size_t)grow * M + col] = v;
                    if (EPI == 2) xs[(size_t)grow * 64 + col] += v;
                }
            }
        }
    }
}

// ---------------------------------------------------------------------------
extern "C" void kernel_launch(void* const* d_in, const int* in_sizes, int n_in,
                              void* d_out, int out_size, void* d_ws, size_t ws_size,
                              hipStream_t stream) {
    (void)n_in; (void)out_size; (void)ws_size;
    const float* X = (const float*)d_in[0];
    const int N = in_sizes[0] / 128;

    const float* fc1_w1 = (const float*)d_in[19];
    const float* fc1_b1 = (const float*)d_in[20];
    const float* fc1_w2 = (const float*)d_in[21];
    const float* fc1_b2 = (const float*)d_in[22];
    const float* fc1_w3 = (const float*)d_in[23];
    const float* fc1_b3 = (const float*)d_in[24];
    const float* fc2_w1 = (const float*)d_in[25];
    const float* fc2_b1 = (const float*)d_in[26];
    const float* fc2_w2 = (const float*)d_in[27];
    const float* fc2_b2 = (const float*)d_in[28];
    const float* fc2_w3 = (const float*)d_in[29];
    const float* fc2_b3 = (const float*)d_in[30];

    float* out = (float*)d_out;
    float* Xs  = out;  // slot 0

    // ---- workspace layout ----
    char* base = (char*)d_ws;
    const size_t Npad = (((size_t)N + 255) / 256) * 256;
    float*          dinv  = (float*)base;                 base += Npad * 4;
    unsigned short* Xbf   = (unsigned short*)base;        base += (size_t)N * 128 * 2;
    unsigned short* t1bf  = (unsigned short*)base;        base += (size_t)N * 256 * 2;  // CSR arena alias
    unsigned short* t2bf  = (unsigned short*)base;        base += (size_t)N * 128 * 2;
    unsigned short* aggbf = (unsigned short*)base;        base += (size_t)N * 128 * 2;
    unsigned short* wtbuf = (unsigned short*)base;

    // transposed bf16 weight slots
    unsigned short* fc1w1t = wtbuf;                // 128*256
    unsigned short* fc1w2t = fc1w1t + 32768;       // 256*128
    unsigned short* fc1w3t = fc1w2t + 32768;       // 128*64
    unsigned short* fc2w1t = fc1w3t + 8192;
    unsigned short* fc2w2t = fc2w1t + 32768;
    unsigned short* fc2w3t = fc2w2t + 32768;
    unsigned short* gwt    = fc2w3t + 8192;        // 3 graphs x 2 x 16384

    const dim3 blk(256);
    const int GR = (N + 127) / 128;      // 782 row blocks
    const int NB = (N + 255) / 256;      // node blocks
    const int GWB = (int)(((size_t)N * 64 + 255) / 256);

    // ---- one-time conversions ----
    xconv<<<(N * 32 + 255) / 256, blk, 0, stream>>>(X, Xbf, N * 32);
    wtrans<<<(128 * 256 + 255) / 256, blk, 0, stream>>>(fc1_w1, fc1w1t, 128, 256);
    wtrans<<<(256 * 128 + 255) / 256, blk, 0, stream>>>(fc1_w2, fc1w2t, 256, 128);
    wtrans<<<(128 * 64 + 255) / 256, blk, 0, stream>>>(fc1_w3, fc1w3t, 128, 64);
    wtrans<<<(128 * 256 + 255) / 256, blk, 0, stream>>>(fc2_w1, fc2w1t, 128, 256);
    wtrans<<<(256 * 128 + 255) / 256, blk, 0, stream>>>(fc2_w2, fc2w2t, 256, 128);
    wtrans<<<(128 * 64 + 255) / 256, blk, 0, stream>>>(fc2_w3, fc2w3t, 128, 64);
    for (int g = 0; g < 3; ++g) {
        wtrans<<<(128 * 128 + 255) / 256, blk, 0, stream>>>(
            (const float*)d_in[3 + 6 * g], gwt + g * 32768, 128, 128);
        wtrans<<<(128 * 128 + 255) / 256, blk, 0, stream>>>(
            (const float*)d_in[5 + 6 * g], gwt + g * 32768 + 16384, 128, 128);
    }

    // ---- X0 = fc1(X) -> Xs ----
    gemm_bf<128, 1, 0><<<dim3(GR, 4), blk, 0, stream>>>(Xbf, fc1w1t, fc1_b1, t1bf, 256, N, nullptr);
    gemm_bf<256, 1, 0><<<dim3(GR, 2), blk, 0, stream>>>(t1bf, fc1w2t, fc1_b2, t2bf, 128, N, nullptr);
    gemm_bf<128, 1, 1><<<dim3(GR, 1), blk, 0, stream>>>(t2bf, fc1w3t, fc1_b3, Xs, 64, N, nullptr);

    // ---- graphs ----
    for (int g = 0; g < 3; ++g) {
        const int*   ei  = (const int*)d_in[1 + 6 * g];
        const int    E   = in_sizes[1 + 6 * g] / 2;
        const int*   srp = ei;
        const int*   dsp = ei + E;
        const float* ew  = (const float*)d_in[2 + 6 * g];
        const float* b1  = (const float*)d_in[4 + 6 * g];
        const float* b2  = (const float*)d_in[6 + 6 * g];
        unsigned short* w1t = gwt + g * 32768;
        unsigned short* w2t = w1t + 16384;

        // CSR arena aliases t1bf (dead between gather2 and fc2_1 writes)
        int*   cnt   = (int*)t1bf;           // N (cursor after scan3)
        int*   rpn   = cnt + N;              // N+1
        int*   colv  = rpn + (N + 1);        // E
        float* normv = (float*)(colv + E);   // E
        int*   bsum  = (int*)(normv + E);    // 512

        init_deg_cnt<<<NB, blk, 0, stream>>>(dinv, cnt, N);
        deg_cnt<<<(E + 255) / 256, blk, 0, stream>>>(dsp, ew, dinv, cnt, E);
        rsqrt_k<<<NB, blk, 0, stream>>>(dinv, N);
        scan1<<<NB, blk, 0, stream>>>(cnt, rpn, bsum, N);
        scan2<<<1, 512, 0, stream>>>(bsum, NB);
        scan3<<<NB, blk, 0, stream>>>(rpn, bsum, cnt, N, E);
        place_k<<<(E + 255) / 256, blk, 0, stream>>>(srp, dsp, ew, dinv, cnt, colv, normv, E);

        // conv1 + conv2 (gather applies bias+relu, bf16)
        gemm_bf<128, 0, 0><<<dim3(GR, 2), blk, 0, stream>>>(Xbf, w1t, nullptr, t2bf, 128, N, nullptr);
        gather_bf<<<GWB, blk, 0, stream>>>(rpn, colv, normv, t2bf, dinv, b1, aggbf, N);
        gemm_bf<128, 0, 0><<<dim3(GR, 2), blk, 0, stream>>>(aggbf, w2t, nullptr, t2bf, 128, N, nullptr);
        gather_bf<<<GWB, blk, 0, stream>>>(rpn, colv, normv, t2bf, dinv, b2, aggbf, N);

        // fc2 head
        gemm_bf<128, 1, 0><<<dim3(GR, 4), blk, 0, stream>>>(aggbf, fc2w1t, fc2_b1, t1bf, 256, N, nullptr);
        gemm_bf<256, 1, 0><<<dim3(GR, 2), blk, 0, stream>>>(t1bf, fc2w2t, fc2_b2, t2bf, 128, N, nullptr);
        gemm_bf<128, 1, 2><<<dim3(GR, 1), blk, 0, stream>>>(
            t2bf, fc2w3t, fc2_b3, out + (size_t)(1 + g) * N * 64, 64, N, Xs);
    }
}

// Round 4
// 1465.421 us; speedup vs baseline: 6.6404x; 1.2873x over previous
//
#include <hip/hip_runtime.h>

// ---------------------------------------------------------------------------
// SubModel_22016002359901: 3x GCN(2 conv) + FC heads, N=100000, F=128, E=1.6M
// Round 4: cut CSR-build atomic traffic (packed 64-bit deg+cnt atomic,
// fused unpack/rsqrt into scan, int2 edge records) + 4-deep gather unroll.
// bf16 MFMA GEMMs unchanged from round 3.
// ---------------------------------------------------------------------------

typedef short bf16x8 __attribute__((ext_vector_type(8)));
typedef float f32x4 __attribute__((ext_vector_type(4)));
typedef unsigned long long ull;

static __device__ __forceinline__ float frelu(float x) { return x > 0.f ? x : 0.f; }

static __device__ __forceinline__ unsigned short f2bf(float f) {
    unsigned int u = __float_as_uint(f);
    u += 0x7fffu + ((u >> 16) & 1u);           // RNE
    return (unsigned short)(u >> 16);
}
static __device__ __forceinline__ float bflo(unsigned int u) {
    return __uint_as_float(u << 16);
}
static __device__ __forceinline__ float bfhi(unsigned int u) {
    return __uint_as_float(u & 0xffff0000u);
}

// ---------------- conversion kernels ----------------
__global__ void xconv(const float* __restrict__ src, unsigned short* __restrict__ dst, int n4) {
    int i = blockIdx.x * 256 + threadIdx.x;
    if (i >= n4) return;
    float4 v = *(const float4*)(src + (size_t)i * 4);
    ushort4 o = {f2bf(v.x), f2bf(v.y), f2bf(v.z), f2bf(v.w)};
    *(ushort4*)(dst + (size_t)i * 4) = o;
}

// dst[m][k] = bf16(src[k][m])
__global__ void wtrans(const float* __restrict__ src, unsigned short* __restrict__ dst,
                       int K, int M) {
    int i = blockIdx.x * 256 + threadIdx.x;
    if (i >= K * M) return;
    int m = i / K, k = i % K;
    dst[i] = f2bf(src[(size_t)k * M + m]);
}

// ---------------- CSR build ----------------
__global__ void zero_pk(ull* __restrict__ pk, int n) {
    int i = blockIdx.x * blockDim.x + threadIdx.x;
    if (i < n) pk[i] = 0ull;
}

// one 64-bit atomic per edge: count in bits [43..], fixed-point(2^20) ew sum below
__global__ void deg_cnt_p(const int* __restrict__ dst, const float* __restrict__ ew,
                          ull* __restrict__ pk, int nE) {
    int e = blockIdx.x * blockDim.x + threadIdx.x;
    if (e < nE) {
        ull inc = (1ull << 43) | (ull)(unsigned int)(ew[e] * 1048576.f + 0.5f);
        atomicAdd(&pk[dst[e]], inc);
    }
}

// fused: unpack pk -> (dinv, cnt) + block-level exclusive scan of cnt
__global__ void scan1p(const ull* __restrict__ pk, float* __restrict__ dinv,
                       int* __restrict__ rp, int* __restrict__ bsum, int n) {
    __shared__ int s[256];
    int i = blockIdx.x * 256 + threadIdx.x;
    int v = 0;
    if (i < n) {
        ull p = pk[i];
        v = (int)(p >> 43);
        float deg = 1.f + (float)(p & ((1ull << 43) - 1ull)) * (1.f / 1048576.f);
        dinv[i] = rsqrtf(deg);
    }
    s[threadIdx.x] = v;
    __syncthreads();
#pragma unroll
    for (int off = 1; off < 256; off <<= 1) {
        int x = (threadIdx.x >= off) ? s[threadIdx.x - off] : 0;
        __syncthreads();
        s[threadIdx.x] += x;
        __syncthreads();
    }
    if (i < n) rp[i] = s[threadIdx.x] - v;           // exclusive within block
    if (threadIdx.x == 255) bsum[blockIdx.x] = s[255];
}

__global__ void scan2(int* __restrict__ bsum, int nb) {   // one block of 512
    __shared__ int s[512];
    int t = threadIdx.x;
    int v = (t < nb) ? bsum[t] : 0;
    s[t] = v;
    __syncthreads();
#pragma unroll
    for (int off = 1; off < 512; off <<= 1) {
        int x = (t >= off) ? s[t - off] : 0;
        __syncthreads();
        s[t] += x;
        __syncthreads();
    }
    if (t < nb) bsum[t] = s[t] - v;
}

__global__ void scan3(int* __restrict__ rp, const int* __restrict__ bsum,
                      int* __restrict__ cursor, int n, int E) {
    int i = blockIdx.x * 256 + threadIdx.x;
    if (i < n) {
        int v = rp[i] + bsum[i >> 8];
        rp[i] = v;
        cursor[i] = v;
    }
    if (i == 0) rp[n] = E;
}

// placement: one int2 {src, norm} write per edge, sorted by dst
__global__ void place_k(const int* __restrict__ src, const int* __restrict__ dst,
                        const float* __restrict__ ew, const float* __restrict__ dinv,
                        int* __restrict__ cursor, int2* __restrict__ ev, int nE) {
    int e = blockIdx.x * blockDim.x + threadIdx.x;
    if (e >= nE) return;
    int s = src[e], d = dst[e];
    int p = atomicAdd(&cursor[d], 1);
    float norm = dinv[s] * ew[e] * dinv[d];
    ev[p] = make_int2(s, __float_as_int(norm));
}

// one wave per node: aggr[n] = relu(bias + dinv^2*h[n] + sum norm*h[col]) (bf16)
__global__ __launch_bounds__(256) void gather_bf(
    const int* __restrict__ rp, const int2* __restrict__ ev,
    const unsigned short* __restrict__ h,
    const float* __restrict__ dinv, const float* __restrict__ bias,
    unsigned short* __restrict__ aggr, int n) {
    int node = (int)(((size_t)blockIdx.x * 256 + threadIdx.x) >> 6);
    if (node >= n) return;
    int lane = threadIdx.x & 63;
    float di = dinv[node];
    float sl = di * di;
    unsigned int hu = *(const unsigned int*)(h + (size_t)node * 128 + lane * 2);
    float2 bv = *(const float2*)(bias + lane * 2);
    float a0x = bv.x + sl * bflo(hu), a0y = bv.y + sl * bfhi(hu);
    float a1x = 0.f, a1y = 0.f, a2x = 0.f, a2y = 0.f, a3x = 0.f, a3y = 0.f;
    int beg = rp[node], end = rp[node + 1];
    int i = beg;
    for (; i + 3 < end; i += 4) {
        int2 e0 = ev[i], e1 = ev[i + 1], e2 = ev[i + 2], e3 = ev[i + 3];
        unsigned int u0 = *(const unsigned int*)(h + (size_t)e0.x * 128 + lane * 2);
        unsigned int u1 = *(const unsigned int*)(h + (size_t)e1.x * 128 + lane * 2);
        unsigned int u2 = *(const unsigned int*)(h + (size_t)e2.x * 128 + lane * 2);
        unsigned int u3 = *(const unsigned int*)(h + (size_t)e3.x * 128 + lane * 2);
        float n0 = __int_as_float(e0.y), n1 = __int_as_float(e1.y);
        float n2 = __int_as_float(e2.y), n3 = __int_as_float(e3.y);
        a0x += n0 * bflo(u0); a0y += n0 * bfhi(u0);
        a1x += n1 * bflo(u1); a1y += n1 * bfhi(u1);
        a2x += n2 * bflo(u2); a2y += n2 * bfhi(u2);
        a3x += n3 * bflo(u3); a3y += n3 * bfhi(u3);
    }
    for (; i < end; ++i) {
        int2 e0 = ev[i];
        unsigned int u0 = *(const unsigned int*)(h + (size_t)e0.x * 128 + lane * 2);
        float n0 = __int_as_float(e0.y);
        a0x += n0 * bflo(u0); a0y += n0 * bfhi(u0);
    }
    float ox = frelu((a0x + a1x) + (a2x + a3x));
    float oy = frelu((a0y + a1y) + (a2y + a3y));
    unsigned int o = (unsigned int)f2bf(ox) | ((unsigned int)f2bf(oy) << 16);
    *(unsigned int*)(aggr + (size_t)node * 128 + lane * 2) = o;
}

// ---------------- bf16 MFMA GEMM (unchanged) ----------------
template<int K, int RELU, int EPI>
__global__ __launch_bounds__(256, 2) void gemm_bf(
    const unsigned short* __restrict__ A, const unsigned short* __restrict__ Wt,
    const float* __restrict__ bias, void* __restrict__ Cout,
    int M, int nrows, float* __restrict__ xs) {
    constexpr int BM = 128, BN = 64, BK = 64;
    __shared__ unsigned short As[BM][BK + 8];
    __shared__ unsigned short Bs[BN][BK + 8];

    const int tid  = threadIdx.x;
    const int wid  = tid >> 6;
    const int lane = tid & 63;
    const int wm   = (wid >> 1) * 64;
    const int wn   = (wid & 1) * 32;
    const int row0 = blockIdx.x * BM;
    const int col0 = blockIdx.y * BN;
    const int lr   = lane & 15;
    const int lk   = (lane >> 4) * 8;

    f32x4 acc[4][2] = {};

    for (int k0 = 0; k0 < K; k0 += BK) {
#pragma unroll
        for (int it = 0; it < 4; ++it) {
            int f = tid + it * 256;
            int r = f >> 3, g = f & 7;
            int grow = row0 + r;
            if (grow >= nrows) grow = nrows - 1;
            bf16x8 v = *(const bf16x8*)(A + (size_t)grow * K + k0 + g * 8);
            *(bf16x8*)&As[r][g * 8] = v;
        }
#pragma unroll
        for (int it = 0; it < 2; ++it) {
            int f = tid + it * 256;
            int nidx = f >> 3, g = f & 7;
            bf16x8 v = *(const bf16x8*)(Wt + (size_t)(col0 + nidx) * K + k0 + g * 8);
            *(bf16x8*)&Bs[nidx][g * 8] = v;
        }
        __syncthreads();
#pragma unroll
        for (int kk = 0; kk < 2; ++kk) {
            bf16x8 af[4], bfv[2];
#pragma unroll
            for (int mi = 0; mi < 4; ++mi)
                af[mi] = *(const bf16x8*)&As[wm + 16 * mi + lr][kk * 32 + lk];
#pragma unroll
            for (int ni = 0; ni < 2; ++ni)
                bfv[ni] = *(const bf16x8*)&Bs[wn + 16 * ni + lr][kk * 32 + lk];
#pragma unroll
            for (int mi = 0; mi < 4; ++mi)
#pragma unroll
                for (int ni = 0; ni < 2; ++ni)
                    acc[mi][ni] = __builtin_amdgcn_mfma_f32_16x16x32_bf16(
                        af[mi], bfv[ni], acc[mi][ni], 0, 0, 0);
        }
        __syncthreads();
    }

    const int dr0 = (lane >> 4) * 4;
#pragma unroll
    for (int ni = 0; ni < 2; ++ni) {
        int col = col0 + wn + 16 * ni + lr;
        float bv = bias ? bias[col] : 0.f;
#pragma unroll
        for (int mi = 0; mi < 4; ++mi) {
#pragma unroll
            for (int r = 0; r < 4; ++r) {
                int grow = row0 + wm + 16 * mi + dr0 + r;
                if (grow >= nrows) continue;
                float v = acc[mi][ni][r] + bv;
                if (RELU) v = frelu(v);
                if (EPI == 0) {
                    ((unsigned short*)Cout)[(size_t)grow * M + col] = f2bf(v);
                } else {
                    ((float*)Cout)[(size_t)grow * M + col] = v;
                    if (EPI == 2) xs[(size_t)grow * 64 + col] += v;
                }
            }
        }
    }
}

// ---------------------------------------------------------------------------
extern "C" void kernel_launch(void* const* d_in, const int* in_sizes, int n_in,
                              void* d_out, int out_size, void* d_ws, size_t ws_size,
                              hipStream_t stream) {
    (void)n_in; (void)out_size; (void)ws_size;
    const float* X = (const float*)d_in[0];
    const int N = in_sizes[0] / 128;

    const float* fc1_w1 = (const float*)d_in[19];
    const float* fc1_b1 = (const float*)d_in[20];
    const float* fc1_w2 = (const float*)d_in[21];
    const float* fc1_b2 = (const float*)d_in[22];
    const float* fc1_w3 = (const float*)d_in[23];
    const float* fc1_b3 = (const float*)d_in[24];
    const float* fc2_w1 = (const float*)d_in[25];
    const float* fc2_b1 = (const float*)d_in[26];
    const float* fc2_w2 = (const float*)d_in[27];
    const float* fc2_b2 = (const float*)d_in[28];
    const float* fc2_w3 = (const float*)d_in[29];
    const float* fc2_b3 = (const float*)d_in[30];

    float* out = (float*)d_out;
    float* Xs  = out;  // slot 0

    // ---- workspace layout ----
    char* base = (char*)d_ws;
    const size_t Npad = (((size_t)N + 255) / 256) * 256;
    float*          dinv  = (float*)base;                 base += Npad * 4;
    unsigned short* Xbf   = (unsigned short*)base;        base += (size_t)N * 128 * 2;
    unsigned short* t1bf  = (unsigned short*)base;        base += (size_t)N * 256 * 2;  // CSR arena alias
    unsigned short* t2bf  = (unsigned short*)base;        base += (size_t)N * 128 * 2;
    unsigned short* aggbf = (unsigned short*)base;        base += (size_t)N * 128 * 2;
    unsigned short* wtbuf = (unsigned short*)base;

    unsigned short* fc1w1t = wtbuf;
    unsigned short* fc1w2t = fc1w1t + 32768;
    unsigned short* fc1w3t = fc1w2t + 32768;
    unsigned short* fc2w1t = fc1w3t + 8192;
    unsigned short* fc2w2t = fc2w1t + 32768;
    unsigned short* fc2w3t = fc2w2t + 32768;
    unsigned short* gwt    = fc2w3t + 8192;

    const dim3 blk(256);
    const int GR = (N + 127) / 128;
    const int NB = (N + 255) / 256;
    const int GWB = (int)(((size_t)N * 64 + 255) / 256);

    // ---- one-time conversions ----
    xconv<<<(N * 32 + 255) / 256, blk, 0, stream>>>(X, Xbf, N * 32);
    wtrans<<<(128 * 256 + 255) / 256, blk, 0, stream>>>(fc1_w1, fc1w1t, 128, 256);
    wtrans<<<(256 * 128 + 255) / 256, blk, 0, stream>>>(fc1_w2, fc1w2t, 256, 128);
    wtrans<<<(128 * 64 + 255) / 256, blk, 0, stream>>>(fc1_w3, fc1w3t, 128, 64);
    wtrans<<<(128 * 256 + 255) / 256, blk, 0, stream>>>(fc2_w1, fc2w1t, 128, 256);
    wtrans<<<(256 * 128 + 255) / 256, blk, 0, stream>>>(fc2_w2, fc2w2t, 256, 128);
    wtrans<<<(128 * 64 + 255) / 256, blk, 0, stream>>>(fc2_w3, fc2w3t, 128, 64);
    for (int g = 0; g < 3; ++g) {
        wtrans<<<(128 * 128 + 255) / 256, blk, 0, stream>>>(
            (const float*)d_in[3 + 6 * g], gwt + g * 32768, 128, 128);
        wtrans<<<(128 * 128 + 255) / 256, blk, 0, stream>>>(
            (const float*)d_in[5 + 6 * g], gwt + g * 32768 + 16384, 128, 128);
    }

    // ---- X0 = fc1(X) -> Xs ----
    gemm_bf<128, 1, 0><<<dim3(GR, 4), blk, 0, stream>>>(Xbf, fc1w1t, fc1_b1, t1bf, 256, N, nullptr);
    gemm_bf<256, 1, 0><<<dim3(GR, 2), blk, 0, stream>>>(t1bf, fc1w2t, fc1_b2, t2bf, 128, N, nullptr);
    gemm_bf<128, 1, 1><<<dim3(GR, 1), blk, 0, stream>>>(t2bf, fc1w3t, fc1_b3, Xs, 64, N, nullptr);

    // ---- graphs ----
    for (int g = 0; g < 3; ++g) {
        const int*   ei  = (const int*)d_in[1 + 6 * g];
        const int    E   = in_sizes[1 + 6 * g] / 2;
        const int*   srp = ei;
        const int*   dsp = ei + E;
        const float* ew  = (const float*)d_in[2 + 6 * g];
        const float* b1  = (const float*)d_in[4 + 6 * g];
        const float* b2  = (const float*)d_in[6 + 6 * g];
        unsigned short* w1t = gwt + g * 32768;
        unsigned short* w2t = w1t + 16384;

        // CSR arena aliases t1bf (dead during conv phase)
        ull*  pk    = (ull*)t1bf;            // N   (8B aligned)
        int*  rpn   = (int*)(pk + N);        // N+2
        int*  cnt   = rpn + (N + 2);         // N (cursor)
        int2* ev    = (int2*)(cnt + N);      // E
        int*  bsum  = (int*)(ev + E);        // 512

        zero_pk<<<NB, blk, 0, stream>>>(pk, N);
        deg_cnt_p<<<(E + 255) / 256, blk, 0, stream>>>(dsp, ew, pk, E);
        scan1p<<<NB, blk, 0, stream>>>(pk, dinv, rpn, bsum, N);
        scan2<<<1, 512, 0, stream>>>(bsum, NB);
        scan3<<<NB, blk, 0, stream>>>(rpn, bsum, cnt, N, E);
        place_k<<<(E + 255) / 256, blk, 0, stream>>>(srp, dsp, ew, dinv, cnt, ev, E);

        // conv1 + conv2 (gather applies bias+relu, bf16)
        gemm_bf<128, 0, 0><<<dim3(GR, 2), blk, 0, stream>>>(Xbf, w1t, nullptr, t2bf, 128, N, nullptr);
        gather_bf<<<GWB, blk, 0, stream>>>(rpn, ev, t2bf, dinv, b1, aggbf, N);
        gemm_bf<128, 0, 0><<<dim3(GR, 2), blk, 0, stream>>>(aggbf, w2t, nullptr, t2bf, 128, N, nullptr);
        gather_bf<<<GWB, blk, 0, stream>>>(rpn, ev, t2bf, dinv, b2, aggbf, N);

        // fc2 head
        gemm_bf<128, 1, 0><<<dim3(GR, 4), blk, 0, stream>>>(aggbf, fc2w1t, fc2_b1, t1bf, 256, N, nullptr);
        gemm_bf<256, 1, 0><<<dim3(GR, 2), blk, 0, stream>>>(t1bf, fc2w2t, fc2_b2, t2bf, 128, N, nullptr);
        gemm_bf<128, 1, 2><<<dim3(GR, 1), blk, 0, stream>>>(
            t2bf, fc2w3t, fc2_b3, out + (size_t)(1 + g) * N * 64, 64, N, Xs);
    }
}